// Round 7
// baseline (209.634 us; speedup 1.0000x reference)
//
#include <hip/hip_runtime.h>
#include <math.h>

// ---------------------------------------------------------------------------
// 2-layer GCN. R19: un-fuse the MLP from agg1 (DS-pipe bound, finally).
// R18 post-mortem: agg1 pinned at ~47us across 4 structural variants because
// the fused 64->16 MLP does 64 ds_read_b32/thread/node-iter (a_s + W2s in a
// 32-iter loop) through the single per-CU DS unit: 16w x 8it x ~86 DS-instr
// x 5.8cyc x 2 blocks = the whole 48us. Gathers were never the limit.
//  - agg1 now ends at lrelu: writes h2in (64-feat bf16 rows, coalesced
//    uint4/lane). No W2s/a_s/MLP loop: per-iter DS ops ~86 -> ~22.
//  - NEW gemm2: MFMA (N x 64 @ 64 x 16) -> t, gemm1's proven fragment
//    layouts, W2 fragments in registers, zero in-loop LDS. ~16MB traffic.
// Unchanged proven pieces: scatterA multisplit (512 bins), degcnt, gemm1,
// LDS csr build + deg-adaptive walk, agg2, bf16 low-half noise trick.
// ---------------------------------------------------------------------------

#define CHUNK 4096        // edges per scatterA block
#define BSHIFT 8          // 256 nodes per bucket
#define BMASK 255
#define CAP 4864          // tmp/csr slots per bucket (mean 4096, +12 sigma)
#define CAPP (CAP + 40)   // LDS csr with fast-path overread pad

typedef __bf16 bf16x8 __attribute__((ext_vector_type(8)));
typedef float f32x4 __attribute__((ext_vector_type(4)));

__device__ __forceinline__ unsigned f2b(float f) {  // fp32 -> bf16 bits (RNE)
  unsigned u = __float_as_uint(f);
  return (u + 0x7FFF + ((u >> 16) & 1)) >> 16;
}

struct f2 { float x, y; };
__device__ __forceinline__ void addu(f2& a, unsigned u) {
  a.x += __uint_as_float(u << 16);
  a.y += __uint_as_float(u);  // low 16 bits are mantissa noise (<=0.4% rel)
}
__device__ __forceinline__ void addu4(f2* a, uint4 g) {
  addu(a[0], g.x); addu(a[1], g.y); addu(a[2], g.z); addu(a[3], g.w);
}

// init bucket cursors + zero rows n of h1s and t (masked-gather targets)
__global__ void binit_kernel(int* __restrict__ gbcursor, int nbc,
                             unsigned* __restrict__ h1s, unsigned* __restrict__ t,
                             int n) {
  int b = blockIdx.x * 256 + threadIdx.x;
  if (b < nbc) gbcursor[b] = b * CAP;
  if (blockIdx.x == 0) {
    if (threadIdx.x < 32) h1s[(size_t)n * 32 + threadIdx.x] = 0u;
    else if (threadIdx.x < 40) t[(size_t)n * 8 + (threadIdx.x - 32)] = 0u;
  }
}

// Block multisplit: pass1 LDS bucket hist; one global atomic per (block,bucket)
// reserves a segment; pass2 places edges via LDS cursors. pack=(src<<8)|(dst&255).
__global__ __launch_bounds__(256) void scatterA_kernel(const int* __restrict__ src,
                                                       const int* __restrict__ dst,
                                                       int E, int nbc,
                                                       int* __restrict__ gbcursor,
                                                       int* __restrict__ tmp) {
  __shared__ int hist[512];
  __shared__ int segcur[512];
  int tid = threadIdx.x;
  int estart = blockIdx.x * CHUNK;
  int eend = min(E, estart + CHUNK);
  hist[tid] = 0;
  hist[tid + 256] = 0;
  __syncthreads();
  for (int i = estart + tid; i < eend; i += 256)
    atomicAdd(&hist[dst[i] >> BSHIFT], 1);
  __syncthreads();
  for (int bb = tid; bb < nbc; bb += 256) {
    int c = hist[bb];
    segcur[bb] = c ? atomicAdd(&gbcursor[bb], c) : 0;
  }
  __syncthreads();
  for (int i = estart + tid; i < eend; i += 256) {
    int d = dst[i];
    int b = d >> BSHIFT;
    int pos = atomicAdd(&segcur[b], 1);
    if (pos < (b + 1) * CAP)  // statistically impossible overflow guard
      tmp[pos] = (src[i] << BSHIFT) | (d & BMASK);
  }
}

// Per-bucket in-degree histogram -> degs (reused by agg1) + dinv (for gemm1).
__global__ __launch_bounds__(256) void degcnt_kernel(const int* __restrict__ tmp,
                                                     const int* __restrict__ gbcursor,
                                                     int* __restrict__ degs,
                                                     float* __restrict__ dinv, int n) {
  __shared__ int nh[256];
  int b = blockIdx.x, tid = threadIdx.x;
  nh[tid] = 0;
  __syncthreads();
  int base = b * CAP;
  int count = min(gbcursor[b] - base, CAP);
  for (int i = tid; i < count; i += 256) atomicAdd(&nh[tmp[base + i] & BMASK], 1);
  __syncthreads();
  int v = (b << BSHIFT) + tid;
  if (v < n) {
    degs[v] = nh[tid];
    dinv[v] = rsqrtf((float)(nh[tid] + 1));
  }
}

// h1s[row] = bf16x2-packed dinv[row] * (x[row] @ W1), via MFMA (R9-proven).
__global__ __launch_bounds__(256, 4) void gemm1_kernel(const float* __restrict__ x,
                                                       const float* __restrict__ W1,
                                                       const float* __restrict__ dinv,
                                                       unsigned* __restrict__ h1s, int n) {
  __shared__ unsigned lds_u[64 * 68 * 2];
  unsigned* xs = lds_u;
  unsigned* wt = lds_u + 64 * 68;
  int tid = threadIdx.x;
  int vb = blockIdx.x * 64;
  int nrows = min(64, n - vb);

  const float4* xg = (const float4*)(x + (size_t)vb * 128);
#pragma unroll
  for (int it = 0; it < 8; ++it) {
    int idx = it * 256 + tid;
    int r = idx >> 5, c2 = idx & 31;
    float4 vv = make_float4(0.f, 0.f, 0.f, 0.f);
    if (r < nrows) vv = xg[idx];
    xs[r * 68 + c2 * 2] = (f2b(vv.y) << 16) | f2b(vv.x);
    xs[r * 68 + c2 * 2 + 1] = (f2b(vv.w) << 16) | f2b(vv.z);
  }
  unsigned short* wt16 = (unsigned short*)wt;
  const float4* wg = (const float4*)W1;
#pragma unroll
  for (int it = 0; it < 8; ++it) {
    int idx = it * 256 + tid;          // k = idx>>4, n0 = (idx&15)*4
    int k = idx >> 4, n0 = (idx & 15) * 4;
    float4 wv = wg[idx];
    wt16[(n0 + 0) * 136 + k] = (unsigned short)f2b(wv.x);
    wt16[(n0 + 1) * 136 + k] = (unsigned short)f2b(wv.y);
    wt16[(n0 + 2) * 136 + k] = (unsigned short)f2b(wv.z);
    wt16[(n0 + 3) * 136 + k] = (unsigned short)f2b(wv.w);
  }
  __syncthreads();

  int lane = tid & 63, wid = tid >> 6;
  int m16 = lane & 15, quad = lane >> 4;
  const unsigned* xp = xs + (wid * 16 + m16) * 68 + quad * 4;
  const unsigned* wp = wt + m16 * 68 + quad * 4;
  f32x4 acc[4] = {};
#pragma unroll
  for (int ks = 0; ks < 4; ++ks) {
    bf16x8 a = *(const bf16x8*)(xp + ks * 16);
#pragma unroll
    for (int nt = 0; nt < 4; ++nt) {
      bf16x8 b = *(const bf16x8*)(wp + nt * 16 * 68 + ks * 16);
      acc[nt] = __builtin_amdgcn_mfma_f32_16x16x32_bf16(a, b, acc[nt], 0, 0, 0);
    }
  }
  int rbase = vb + wid * 16 + quad * 4;
  float dvv[4];
#pragma unroll
  for (int reg = 0; reg < 4; ++reg) {
    int row = rbase + reg;
    dvv[reg] = (row < n) ? dinv[row] : 0.f;
  }
  unsigned short* h16 = (unsigned short*)h1s;
#pragma unroll
  for (int nt = 0; nt < 4; ++nt) {
    int col = nt * 16 + m16;
#pragma unroll
    for (int reg = 0; reg < 4; ++reg) {
      int row = rbase + reg;
      if (row < n)
        h16[(size_t)row * 64 + col] = (unsigned short)f2b(dvv[reg] * acc[nt][reg]);
    }
  }
}

// NQ-tier gather batch for agg1: covers slots [0, 8*NQ) of the node's edge
// list. lcsr reads up to rs+8*NQ-1 (pad-safe); masked slots pull zero row n.
template <int NQ>
__device__ __forceinline__ void gatherTier1(const uint4* __restrict__ h1s4,
                                            const int* lcsr, int rs, int e1,
                                            int e, int c, int n, f2* a0) {
  int cv0[NQ], cv1[NQ];
#pragma unroll
  for (int q = 0; q < NQ; ++q) {
    cv0[q] = lcsr[rs + q * 8 + e];
    cv1[q] = lcsr[rs + q * 8 + 4 + e];
  }
  uint4 g[2 * NQ];
#pragma unroll
  for (int q = 0; q < NQ; ++q) {
    int k0 = rs + q * 8 + e, k1 = k0 + 4;
    int s0 = (k0 < e1) ? cv0[q] : n;
    int s1 = (k1 < e1) ? cv1[q] : n;
    g[2 * q] = h1s4[(size_t)s0 * 8 + c];
    g[2 * q + 1] = h1s4[(size_t)s1 * 8 + c];
  }
#pragma unroll
  for (int k = 0; k < 2 * NQ; ++k) addu4(a0, g[k]);
}

// One 1024-thr block per 256-node bucket: load degs -> scan -> LDS-cursor
// scatter -> coalesced csr dump -> walk. Walk: half-wave per node; sub=lane&31,
// e=sub>>3, c=sub&7. Deg-adaptive tiers 16/24/32; tail for deg>32. Ends at
// lrelu: h2in[v] = bf16x2-packed lrelu(dinv*agg + b1) (64 features, uint4/lane).
__global__ __launch_bounds__(1024) void agg1_fused_kernel(
    const int* __restrict__ tmp, const int* __restrict__ gbcursor,
    const uint4* __restrict__ h1s4, const float* __restrict__ dinv,
    const float* __restrict__ b1, const int* __restrict__ degs,
    int* __restrict__ row_start, int* __restrict__ csr,
    unsigned* __restrict__ h2in, int n) {
  __shared__ int lcsr[CAPP];       // 19.6KB
  __shared__ int nh[256];
  __shared__ int rs_s[256];
  __shared__ int lcur[256];
  __shared__ float b1s[64];
  int b = blockIdx.x, tid = threadIdx.x;
  int base = b * CAP;
  int count = min(gbcursor[b] - base, CAP);

  if (tid < 256) {
    int v = (b << BSHIFT) + tid;
    int d = (v < n) ? degs[v] : 0;
    nh[tid] = d;
    rs_s[tid] = d;
  }
  if (tid < 64) b1s[tid] = b1[tid];
  __syncthreads();
  // exclusive scan of nh over 256
  for (int off = 1; off < 256; off <<= 1) {
    int a = 0;
    if (tid < 256) { a = rs_s[tid]; if (tid >= off) a += rs_s[tid - off]; }
    __syncthreads();
    if (tid < 256) rs_s[tid] = a;
    __syncthreads();
  }
  if (tid < 256) {
    int e0 = rs_s[tid] - nh[tid];   // exclusive prefix (bucket-local)
    lcur[tid] = e0;
    rs_s[tid] = e0;
    int v = (b << BSHIFT) + tid;
    if (v < n) row_start[v] = base + e0;
  }
  __syncthreads();
  // scatter into LDS csr
  for (int i = tid; i < count; i += 1024) {
    int val = tmp[base + i];
    int pos = atomicAdd(&lcur[val & BMASK], 1);
    lcsr[pos] = val >> BSHIFT;
  }
  __syncthreads();
  // coalesced dump for agg2
  for (int i = tid; i < count; i += 1024) csr[base + i] = lcsr[i];

  // walk
  int wave = tid >> 6, lane = tid & 63;
  int half = lane >> 5, sub = lane & 31;
  int e = sub >> 3, c = sub & 7;

#pragma unroll 1
  for (int it = 0; it < 8; ++it) {
    int nl = wave * 16 + it * 2 + half;       // 0..255
    int v = (b << BSHIFT) + nl;
    bool valid = (v < n);                     // half-uniform
    int rs = rs_s[nl];
    int deg = nh[nl];                         // 0 for v >= n
    int e1 = rs + deg;
    float dv = valid ? dinv[valid ? v : 0] : 0.f;

    f2 a0[4];
#pragma unroll
    for (int k = 0; k < 4; ++k) a0[k] = {0.f, 0.f};
    {  // self loop: e==0 lanes pull row v, others pull zero row
      int s = (valid && sub < 8) ? v : n;
      addu4(a0, h1s4[(size_t)s * 8 + c]);
    }
    // deg-adaptive fast path (wave-uniform tier on max of the two halves)
    int dm = max(deg, __shfl_xor(deg, 32, 64));
    int start;
    if (dm <= 16) {
      gatherTier1<2>(h1s4, lcsr, rs, e1, e, c, n, a0);
      start = 16;
    } else if (dm <= 24) {
      gatherTier1<3>(h1s4, lcsr, rs, e1, e, c, n, a0);
      start = 24;
    } else {
      gatherTier1<4>(h1s4, lcsr, rs, e1, e, c, n, a0);
      start = 32;
    }
    // tail: deg > 32 (rare)
    int i = rs + start;
    while (__any(i < e1)) {
      int i0 = i + e, i1 = i + 4 + e;
      int s0v = lcsr[i0];
      int s1v = lcsr[i1];
      int s0 = (i0 < e1) ? s0v : n;
      int s1 = (i1 < e1) ? s1v : n;
      addu4(a0, h1s4[(size_t)s0 * 8 + c]);
      addu4(a0, h1s4[(size_t)s1 * 8 + c]);
      i += 8;
    }
    // reduce across e (lane bits 3,4 within half)
#pragma unroll
    for (int m = 8; m <= 16; m <<= 1) {
#pragma unroll
      for (int k = 0; k < 4; ++k) {
        a0[k].x += __shfl_xor(a0[k].x, m, 64);
        a0[k].y += __shfl_xor(a0[k].y, m, 64);
      }
    }
    if (valid && sub < 8) {  // e==0; c==sub; features 8c..8c+7
      float z[8];
#pragma unroll
      for (int k = 0; k < 4; ++k) {
        float z0 = fmaf(dv, a0[k].x, b1s[8 * sub + 2 * k]);
        float z1 = fmaf(dv, a0[k].y, b1s[8 * sub + 2 * k + 1]);
        z[2 * k] = fmaxf(z0, 0.2f * z0);
        z[2 * k + 1] = fmaxf(z1, 0.2f * z1);
      }
      uint4 o;
      o.x = (f2b(z[1]) << 16) | f2b(z[0]);
      o.y = (f2b(z[3]) << 16) | f2b(z[2]);
      o.z = (f2b(z[5]) << 16) | f2b(z[4]);
      o.w = (f2b(z[7]) << 16) | f2b(z[6]);
      ((uint4*)h2in)[(size_t)v * 8 + sub] = o;
    }
  }
}

// t[row] = bf16x2-packed dinv[row] * (h2in[row] @ W2), via MFMA.
// 256 thr = 4 waves; per wave per pass: 16 rows x 16 cols, K=64 (2 mfma).
// W2 fragments in registers (gemm1's proven b-frag layout); no in-loop LDS.
__global__ __launch_bounds__(256) void gemm2_kernel(const uint4* __restrict__ h2in4,
                                                    const float* __restrict__ W2,
                                                    const float* __restrict__ dinv,
                                                    unsigned* __restrict__ t, int n) {
  int tid = threadIdx.x;
  int lane = tid & 63, wid = tid >> 6;
  int m16 = lane & 15, quad = lane >> 4;
  // B-frags: lane holds W2[k = ks*32 + quad*8 + j][col = m16], j=0..7
  union { bf16x8 v; unsigned short s[8]; } bu0, bu1;
#pragma unroll
  for (int j = 0; j < 8; ++j) {
    bu0.s[j] = (unsigned short)f2b(W2[(quad * 8 + j) * 16 + m16]);
    bu1.s[j] = (unsigned short)f2b(W2[(32 + quad * 8 + j) * 16 + m16]);
  }
#pragma unroll 1
  for (int pass = 0; pass < 4; ++pass) {
    int rt = blockIdx.x * 256 + pass * 64 + wid * 16;
    int row_a = rt + m16;
    int ra = (row_a < n) ? row_a : 0;
    // A-frags: lane holds h2in[row = rt+m16][k = ks*32 + quad*8 + j]
    uint4 av0 = h2in4[(size_t)ra * 8 + quad];
    uint4 av1 = h2in4[(size_t)ra * 8 + 4 + quad];
    f32x4 acc = {};
    acc = __builtin_amdgcn_mfma_f32_16x16x32_bf16(*(const bf16x8*)&av0, bu0.v, acc, 0, 0, 0);
    acc = __builtin_amdgcn_mfma_f32_16x16x32_bf16(*(const bf16x8*)&av1, bu1.v, acc, 0, 0, 0);
    // C[row = rt + quad*4 + reg][col = m16]; fold dinv, pack bf16 col-pairs
#pragma unroll
    for (int reg = 0; reg < 4; ++reg) {
      int row = rt + quad * 4 + reg;
      float dv = (row < n) ? dinv[row] : 0.f;
      float val = dv * acc[reg];
      float other = __shfl_xor(val, 1, 64);
      if (!(m16 & 1) && row < n)
        t[(size_t)row * 8 + (m16 >> 1)] = (f2b(other) << 16) | f2b(val);
    }
  }
}

// 16 lanes per node, bf16 t rows (32B). sub=lane&15: e=sub>>1 (8 edge slots),
// c=sub&1. Fast path deg<=32: 4 csr loads + 4 independent gathers. Row n of t
// is zeros. log_softmax via 8-local + xor-1 lane reduce. (R16-proven form.)
__global__ __launch_bounds__(256) void agg2_kernel(const uint4* __restrict__ t4,
                                                   const float* __restrict__ dinv,
                                                   const int* __restrict__ row_start,
                                                   const int* __restrict__ degs,
                                                   const int* __restrict__ csr,
                                                   const float* __restrict__ b2,
                                                   float* __restrict__ out, int n) {
  int idx = blockIdx.x * 256 + threadIdx.x;
  int v = idx >> 4;
  if (v >= n) return;
  int sub = threadIdx.x & 15;
  int e = sub >> 1, c = sub & 1;
  float dv = dinv[v];
  int rs = row_start[v], e1 = rs + degs[v];
  f2 A0[4];
#pragma unroll
  for (int k = 0; k < 4; ++k) A0[k] = {0.f, 0.f};
  {  // self loop
    int s = (e == 0) ? v : n;
    addu4(A0, t4[(size_t)s * 2 + c]);
  }
  int cv[4];
#pragma unroll
  for (int q = 0; q < 4; ++q) cv[q] = csr[rs + q * 8 + e];
  uint4 g[4];
#pragma unroll
  for (int q = 0; q < 4; ++q) {
    int k = rs + q * 8 + e;
    int s = (k < e1) ? cv[q] : n;
    g[q] = t4[(size_t)s * 2 + c];
  }
#pragma unroll
  for (int k = 0; k < 4; ++k) addu4(A0, g[k]);
  // tail: deg > 32 (rare; node-uniform)
  int i = rs + 32;
  while (i < e1) {
    int i0 = i + e;
    int sv = csr[i0];
    int s = (i0 < e1) ? sv : n;
    addu4(A0, t4[(size_t)s * 2 + c]);
    i += 8;
  }
#pragma unroll
  for (int m = 2; m <= 8; m <<= 1) {  // reduce across e-groups (sub bits 1..3)
#pragma unroll
    for (int k = 0; k < 4; ++k) {
      A0[k].x += __shfl_xor(A0[k].x, m, 64);
      A0[k].y += __shfl_xor(A0[k].y, m, 64);
    }
  }
  float4 bb0 = ((const float4*)b2)[c * 2];
  float4 bb1 = ((const float4*)b2)[c * 2 + 1];
  float z[8];
  z[0] = fmaf(dv, A0[0].x, bb0.x); z[1] = fmaf(dv, A0[0].y, bb0.y);
  z[2] = fmaf(dv, A0[1].x, bb0.z); z[3] = fmaf(dv, A0[1].y, bb0.w);
  z[4] = fmaf(dv, A0[2].x, bb1.x); z[5] = fmaf(dv, A0[2].y, bb1.y);
  z[6] = fmaf(dv, A0[3].x, bb1.z); z[7] = fmaf(dv, A0[3].y, bb1.w);
  float mx = z[0];
#pragma unroll
  for (int q = 1; q < 8; ++q) mx = fmaxf(mx, z[q]);
  mx = fmaxf(mx, __shfl_xor(mx, 1, 64));  // combine c halves
  float ss = 0.f;
#pragma unroll
  for (int q = 0; q < 8; ++q) ss += expf(z[q] - mx);
  ss += __shfl_xor(ss, 1, 64);
  float lg = mx + logf(ss);
  if (e == 0) {
    float4 r0 = make_float4(z[0] - lg, z[1] - lg, z[2] - lg, z[3] - lg);
    float4 r1 = make_float4(z[4] - lg, z[5] - lg, z[6] - lg, z[7] - lg);
    float4* o = (float4*)out + (size_t)v * 4 + c * 2;
    o[0] = r0;
    o[1] = r1;
  }
}

extern "C" void kernel_launch(void* const* d_in, const int* in_sizes, int n_in,
                              void* d_out, int out_size, void* d_ws, size_t ws_size,
                              hipStream_t stream) {
  const float* x = (const float*)d_in[0];
  const int* edge_index = (const int*)d_in[1];
  const float* W1 = (const float*)d_in[2];
  const float* b1 = (const float*)d_in[3];
  const float* W2 = (const float*)d_in[4];
  const float* b2 = (const float*)d_in[5];
  float* out = (float*)d_out;

  int N_ = in_sizes[0] / 128;
  int E_ = in_sizes[1] / 2;
  const int* src = edge_index;
  const int* dst = edge_index + E_;
  int NBc = (N_ + BMASK) >> BSHIFT;  // 391 buckets of 256 nodes (<= 512)

  char* ws = (char*)d_ws;
  size_t off = 0;
  auto take = [&](size_t bytes) {
    void* p = ws + off;
    off += (bytes + 255) & ~(size_t)255;
    return p;
  };
  unsigned* h1s = (unsigned*)take(((size_t)N_ + 1) * 32 * 4);   // +1 zero row
  unsigned* h2in = (unsigned*)take(((size_t)N_ + 256) * 32 * 4); // 64-feat bf16
  unsigned* t = (unsigned*)take(((size_t)N_ + 1) * 8 * 4);      // +1 zero row
  int* tmp = (int*)take((size_t)NBc * CAP * 4);
  int* csr = (int*)take(((size_t)NBc * CAP + 64) * 4);          // padded layout
  float* dinv = (float*)take((size_t)N_ * 4);
  int* degs = (int*)take((size_t)N_ * 4);
  int* row_start = (int*)take((size_t)N_ * 4);
  int* gbcursor = (int*)take((size_t)NBc * 4);
  (void)ws_size;

  binit_kernel<<<(NBc + 255) / 256, 256, 0, stream>>>(gbcursor, NBc, h1s, t, N_);
  scatterA_kernel<<<(E_ + CHUNK - 1) / CHUNK, 256, 0, stream>>>(src, dst, E_, NBc,
                                                                gbcursor, tmp);
  degcnt_kernel<<<NBc, 256, 0, stream>>>(tmp, gbcursor, degs, dinv, N_);
  gemm1_kernel<<<(N_ + 63) / 64, 256, 0, stream>>>(x, W1, dinv, h1s, N_);
  agg1_fused_kernel<<<NBc, 1024, 0, stream>>>(tmp, gbcursor, (const uint4*)h1s,
                                              dinv, b1, degs, row_start, csr,
                                              h2in, N_);
  gemm2_kernel<<<(N_ + 255) / 256, 256, 0, stream>>>((const uint4*)h2in, W2, dinv,
                                                     t, N_);
  agg2_kernel<<<(N_ * 16 + 255) / 256, 256, 0, stream>>>((const uint4*)t, dinv,
                                                         row_start, degs, csr,
                                                         b2, out, N_);
}

// Round 8
// 204.879 us; speedup vs baseline: 1.0232x; 1.0232x over previous
//
#include <hip/hip_runtime.h>
#include <math.h>

// ---------------------------------------------------------------------------
// 2-layer GCN. R20: overlap the build pipeline with gemm1; re-fuse the MLP.
// R19 post-mortem: agg1 invariant at 46.5us across 5 variants -> it is at the
// random-gather memory wall (FETCH 80MB = 8 XCD-L2s each re-missing the
// random 12.8MB h1s; ~2.2TB/s for that stream). MLP fusion was FREE (hidden
// under stalls) -> revert gemm2 split. Attack the ~155us OUTSIDE agg1:
//  - combo kernel: blocks [0,nSc) run scatterA (multisplit by dst>>9, CHUNK
//    8192); blocks [nSc,..) run gemm1u = MFMA x@W1 -> UNSCALED fp32 h1u
//    (no dinv dependency -> the two phases overlap in one launch).
//  - degcnt_scale: per-bucket hist -> degs/dinv, then h1s = bf16(dinv*h1u)
//    (fp32 read, single rounding -- same precision as before).
//  - agg1_fused: R17's proven walk (tiers 16/24/32) + fused b1/lrelu/MLP
//    epilogue; nh loaded from degs (no re-hist). -> t bf16.
//  - agg2: R16-proven fixed-32 node-parallel form.
// Workspace: h1u (25.6MB) aliases {csr,t} (written later, h1u dead by then).
// ---------------------------------------------------------------------------

#define CHUNK 8192        // edges per scatterA block (196 blocks for E=1.6M)
#define BSHIFT 9          // 512 nodes per bucket
#define BMASK 511
#define CAP 9216          // tmp/csr slots per bucket (mean 8192, +11 sigma)
#define CAPP (CAP + 40)   // LDS csr with fast-path overread pad

typedef __bf16 bf16x8 __attribute__((ext_vector_type(8)));
typedef float f32x4 __attribute__((ext_vector_type(4)));

__device__ __forceinline__ unsigned f2b(float f) {  // fp32 -> bf16 bits (RNE)
  unsigned u = __float_as_uint(f);
  return (u + 0x7FFF + ((u >> 16) & 1)) >> 16;
}

struct f2 { float x, y; };
__device__ __forceinline__ void addu(f2& a, unsigned u) {
  a.x += __uint_as_float(u << 16);
  a.y += __uint_as_float(u);  // low 16 bits are mantissa noise (<=0.4% rel)
}
__device__ __forceinline__ void addu4(f2* a, uint4 g) {
  addu(a[0], g.x); addu(a[1], g.y); addu(a[2], g.z); addu(a[3], g.w);
}

// init bucket cursors + zero row n of h1s (t's zero row is set in agg1:
// t aliases h1u which is still live here)
__global__ void binit_kernel(int* __restrict__ gbcursor, int nbc,
                             unsigned* __restrict__ h1s, int n) {
  int b = blockIdx.x * 256 + threadIdx.x;
  if (b < nbc) gbcursor[b] = b * CAP;
  if (blockIdx.x == 0 && threadIdx.x < 32) h1s[(size_t)n * 32 + threadIdx.x] = 0u;
}

// Combo: blocks [0,nSc) = scatterA multisplit; blocks [nSc,..) = gemm1u.
// Shared buffer unioned between the two bodies.
__global__ __launch_bounds__(256, 4) void combo_kernel(
    const int* __restrict__ src, const int* __restrict__ dst, int E, int nbc,
    int nSc, int* __restrict__ gbcursor, int* __restrict__ tmp,
    const float* __restrict__ x, const float* __restrict__ W1,
    float* __restrict__ h1u, int n) {
  __shared__ unsigned shbuf[64 * 68 * 2];   // 34.8KB (gemm1u needs all of it)
  int tid = threadIdx.x;

  if ((int)blockIdx.x < nSc) {
    // ----- scatterA body: pass1 LDS bucket hist; one global atomic per
    // (block,bucket) reserves a segment; pass2 places edges via LDS cursors.
    // pack = (src<<9) | (dst&511).
    int* hist = (int*)shbuf;
    int* segcur = hist + 256;
    int estart = blockIdx.x * CHUNK;
    int eend = min(E, estart + CHUNK);
    hist[tid] = 0;
    __syncthreads();
    for (int i = estart + tid; i < eend; i += 256)
      atomicAdd(&hist[dst[i] >> BSHIFT], 1);
    __syncthreads();
    if (tid < nbc) {
      int c = hist[tid];
      segcur[tid] = c ? atomicAdd(&gbcursor[tid], c) : 0;
    }
    __syncthreads();
    for (int i = estart + tid; i < eend; i += 256) {
      int d = dst[i];
      int b = d >> BSHIFT;
      int pos = atomicAdd(&segcur[b], 1);
      if (pos < (b + 1) * CAP)  // statistically impossible overflow guard
        tmp[pos] = (src[i] << BSHIFT) | (d & BMASK);
    }
  } else {
    // ----- gemm1u body: h1u[row] = fp32 (x[row] @ W1), UNSCALED (R9-proven
    // MFMA layout; dinv applied later in degcnt_scale).
    unsigned* xs = shbuf;
    unsigned* wt = shbuf + 64 * 68;
    int vb = ((int)blockIdx.x - nSc) * 64;
    int nrows = min(64, n - vb);

    const float4* xg = (const float4*)(x + (size_t)vb * 128);
#pragma unroll
    for (int it = 0; it < 8; ++it) {
      int idx = it * 256 + tid;
      int r = idx >> 5, c2 = idx & 31;
      float4 vv = make_float4(0.f, 0.f, 0.f, 0.f);
      if (r < nrows) vv = xg[idx];
      xs[r * 68 + c2 * 2] = (f2b(vv.y) << 16) | f2b(vv.x);
      xs[r * 68 + c2 * 2 + 1] = (f2b(vv.w) << 16) | f2b(vv.z);
    }
    unsigned short* wt16 = (unsigned short*)wt;
    const float4* wg = (const float4*)W1;
#pragma unroll
    for (int it = 0; it < 8; ++it) {
      int idx = it * 256 + tid;          // k = idx>>4, n0 = (idx&15)*4
      int k = idx >> 4, n0 = (idx & 15) * 4;
      float4 wv = wg[idx];
      wt16[(n0 + 0) * 136 + k] = (unsigned short)f2b(wv.x);
      wt16[(n0 + 1) * 136 + k] = (unsigned short)f2b(wv.y);
      wt16[(n0 + 2) * 136 + k] = (unsigned short)f2b(wv.z);
      wt16[(n0 + 3) * 136 + k] = (unsigned short)f2b(wv.w);
    }
    __syncthreads();

    int lane = tid & 63, wid = tid >> 6;
    int m16 = lane & 15, quad = lane >> 4;
    const unsigned* xp = xs + (wid * 16 + m16) * 68 + quad * 4;
    const unsigned* wp = wt + m16 * 68 + quad * 4;
    f32x4 acc[4] = {};
#pragma unroll
    for (int ks = 0; ks < 4; ++ks) {
      bf16x8 a = *(const bf16x8*)(xp + ks * 16);
#pragma unroll
      for (int nt = 0; nt < 4; ++nt) {
        bf16x8 b = *(const bf16x8*)(wp + nt * 16 * 68 + ks * 16);
        acc[nt] = __builtin_amdgcn_mfma_f32_16x16x32_bf16(a, b, acc[nt], 0, 0, 0);
      }
    }
    int rbase = vb + wid * 16 + quad * 4;
#pragma unroll
    for (int nt = 0; nt < 4; ++nt) {
      int col = nt * 16 + m16;
#pragma unroll
      for (int reg = 0; reg < 4; ++reg) {
        int row = rbase + reg;
        if (row < n) h1u[(size_t)row * 64 + col] = acc[nt][reg];
      }
    }
  }
}

// Per-bucket: in-degree hist -> degs + dinv, then scale h1u (fp32) -> h1s
// (bf16x2-packed dinv[row] * h1u[row]). 512 thr per 512-node bucket.
__global__ __launch_bounds__(512) void degcnt_scale_kernel(
    const int* __restrict__ tmp, const int* __restrict__ gbcursor,
    const float4* __restrict__ h1u4, int* __restrict__ degs,
    float* __restrict__ dinv, unsigned* __restrict__ h1s, int n) {
  __shared__ int nh[512];
  __shared__ float dl[512];
  int b = blockIdx.x, tid = threadIdx.x;
  nh[tid] = 0;
  __syncthreads();
  int base = b * CAP;
  int count = min(gbcursor[b] - base, CAP);
  for (int i = tid; i < count; i += 512) atomicAdd(&nh[tmp[base + i] & BMASK], 1);
  __syncthreads();
  int v0 = (b << BSHIFT) + tid;
  float dvv = rsqrtf((float)(nh[tid] + 1));
  dl[tid] = dvv;
  if (v0 < n) {
    degs[v0] = nh[tid];
    dinv[v0] = dvv;
  }
  __syncthreads();
  // scale: 512 rows x 16 float4 each = 8192 float4 -> 16 iters
  uint2* h1s2 = (uint2*)h1s;
#pragma unroll 4
  for (int it = 0; it < 16; ++it) {
    int idx = it * 512 + tid;
    int rl = idx >> 4, q = idx & 15;
    int v = (b << BSHIFT) + rl;
    if (v < n) {
      float4 vv = h1u4[(size_t)v * 16 + q];
      float dv = dl[rl];
      uint2 o;
      o.x = (f2b(dv * vv.y) << 16) | f2b(dv * vv.x);
      o.y = (f2b(dv * vv.w) << 16) | f2b(dv * vv.z);
      h1s2[(size_t)v * 16 + q] = o;
    }
  }
}

// NQ-tier gather batch for agg1: covers slots [0, 8*NQ) of the node's edge
// list. lcsr reads up to rs+8*NQ-1 (pad-safe); masked slots pull zero row n.
template <int NQ>
__device__ __forceinline__ void gatherTier1(const uint4* __restrict__ h1s4,
                                            const int* lcsr, int rs, int e1,
                                            int e, int c, int n, f2* a0) {
  int cv0[NQ], cv1[NQ];
#pragma unroll
  for (int q = 0; q < NQ; ++q) {
    cv0[q] = lcsr[rs + q * 8 + e];
    cv1[q] = lcsr[rs + q * 8 + 4 + e];
  }
  uint4 g[2 * NQ];
#pragma unroll
  for (int q = 0; q < NQ; ++q) {
    int k0 = rs + q * 8 + e, k1 = k0 + 4;
    int s0 = (k0 < e1) ? cv0[q] : n;
    int s1 = (k1 < e1) ? cv1[q] : n;
    g[2 * q] = h1s4[(size_t)s0 * 8 + c];
    g[2 * q + 1] = h1s4[(size_t)s1 * 8 + c];
  }
#pragma unroll
  for (int k = 0; k < 2 * NQ; ++k) addu4(a0, g[k]);
}

// One 1024-thr block per 512-node bucket: load degs -> scan -> LDS-cursor
// scatter -> coalesced csr dump -> walk (half-wave per node, deg-adaptive
// tiers 16/24/32, fused b1 + lrelu + MLP(64->16)) -> t bf16. (R17-proven.)
__global__ __launch_bounds__(1024) void agg1_fused_kernel(
    const int* __restrict__ tmp, const int* __restrict__ gbcursor,
    const uint4* __restrict__ h1s4, const float* __restrict__ dinv,
    const float* __restrict__ b1, const float* __restrict__ W2,
    const int* __restrict__ degs, int* __restrict__ row_start,
    int* __restrict__ csr, unsigned* __restrict__ t, int n) {
  __shared__ int lcsr[CAPP];       // 37KB
  __shared__ int nh[512];
  __shared__ int rs_s[512];
  __shared__ int lcur[512];
  __shared__ float W2s[64 * 17];
  __shared__ float b1s[64];
  __shared__ float a_s[16][2][64];
  int b = blockIdx.x, tid = threadIdx.x;
  int base = b * CAP;
  int count = min(gbcursor[b] - base, CAP);

  if (tid < 512) {
    int v = (b << BSHIFT) + tid;
    int d = (v < n) ? degs[v] : 0;
    nh[tid] = d;
    rs_s[tid] = d;
  }
  W2s[(tid >> 4) * 17 + (tid & 15)] = W2[tid];   // 1024 == 64*16
  if (tid < 64) b1s[tid] = b1[tid];
  if (b == 0 && tid >= 64 && tid < 72)           // zero row n of t (aliased
    t[(size_t)n * 8 + (tid - 64)] = 0u;          //  region: safe only now)
  __syncthreads();
  // exclusive scan of nh over 512
  for (int off = 1; off < 512; off <<= 1) {
    int a = 0;
    if (tid < 512) { a = rs_s[tid]; if (tid >= off) a += rs_s[tid - off]; }
    __syncthreads();
    if (tid < 512) rs_s[tid] = a;
    __syncthreads();
  }
  if (tid < 512) {
    int e0 = rs_s[tid] - nh[tid];   // exclusive prefix (bucket-local)
    lcur[tid] = e0;
    rs_s[tid] = e0;
    int v = (b << BSHIFT) + tid;
    if (v < n) row_start[v] = base + e0;
  }
  __syncthreads();
  // scatter into LDS csr
  for (int i = tid; i < count; i += 1024) {
    int val = tmp[base + i];
    int pos = atomicAdd(&lcur[val & BMASK], 1);
    lcsr[pos] = val >> BSHIFT;
  }
  __syncthreads();
  // coalesced dump for agg2
  for (int i = tid; i < count; i += 1024) csr[base + i] = lcsr[i];

  // walk
  int wave = tid >> 6, lane = tid & 63;
  int half = lane >> 5, sub = lane & 31;
  int e = sub >> 3, c = sub & 7;
  int j = sub & 15, grp = (sub >> 4) & 1;

#pragma unroll 1
  for (int it = 0; it < 16; ++it) {
    int nl = wave * 32 + it * 2 + half;       // 0..511
    int v = (b << BSHIFT) + nl;
    bool valid = (v < n);                     // half-uniform
    int rs = rs_s[nl];
    int deg = nh[nl];                         // 0 for v >= n
    int e1 = rs + deg;
    float dv = valid ? dinv[valid ? v : 0] : 0.f;

    f2 a0[4];
#pragma unroll
    for (int k = 0; k < 4; ++k) a0[k] = {0.f, 0.f};
    {  // self loop: e==0 lanes pull row v, others pull zero row
      int s = (valid && sub < 8) ? v : n;
      addu4(a0, h1s4[(size_t)s * 8 + c]);
    }
    // deg-adaptive fast path (wave-uniform tier on max of the two halves)
    int dm = max(deg, __shfl_xor(deg, 32, 64));
    int start;
    if (dm <= 16) {
      gatherTier1<2>(h1s4, lcsr, rs, e1, e, c, n, a0);
      start = 16;
    } else if (dm <= 24) {
      gatherTier1<3>(h1s4, lcsr, rs, e1, e, c, n, a0);
      start = 24;
    } else {
      gatherTier1<4>(h1s4, lcsr, rs, e1, e, c, n, a0);
      start = 32;
    }
    // tail: deg > 32 (rare)
    int i = rs + start;
    while (__any(i < e1)) {
      int i0 = i + e, i1 = i + 4 + e;
      int s0v = lcsr[i0];
      int s1v = lcsr[i1];
      int s0 = (i0 < e1) ? s0v : n;
      int s1 = (i1 < e1) ? s1v : n;
      addu4(a0, h1s4[(size_t)s0 * 8 + c]);
      addu4(a0, h1s4[(size_t)s1 * 8 + c]);
      i += 8;
    }
    // reduce across e (lane bits 3,4 within half)
#pragma unroll
    for (int m = 8; m <= 16; m <<= 1) {
#pragma unroll
      for (int k = 0; k < 4; ++k) {
        a0[k].x += __shfl_xor(a0[k].x, m, 64);
        a0[k].y += __shfl_xor(a0[k].y, m, 64);
      }
    }
    if (sub < 8) {  // e==0; c==sub; features 8c..8c+7
#pragma unroll
      for (int k = 0; k < 4; ++k) {
        float z0 = fmaf(dv, a0[k].x, b1s[8 * sub + 2 * k]);
        float z1 = fmaf(dv, a0[k].y, b1s[8 * sub + 2 * k + 1]);
        a_s[wave][half][8 * sub + 2 * k] = fmaxf(z0, 0.2f * z0);
        a_s[wave][half][8 * sub + 2 * k + 1] = fmaxf(z1, 0.2f * z1);
      }
    }
    // MLP 64->16: each half-lane sums 32 features (grp*16 and 32+grp*16)
    float p = 0.f;
#pragma unroll
    for (int q = 0; q < 16; ++q) {
      int f = grp * 16 + q;
      p = fmaf(a_s[wave][half][f], W2s[f * 17 + j], p);
    }
#pragma unroll
    for (int q = 0; q < 16; ++q) {
      int f = 32 + grp * 16 + q;
      p = fmaf(a_s[wave][half][f], W2s[f * 17 + j], p);
    }
    p += __shfl_xor(p, 16, 64);  // combine grp halves (lane bit 4)
    float pv = dv * p;
    float po = __shfl_xor(pv, 1, 64);
    if (valid && sub < 16 && !(sub & 1))
      t[(size_t)v * 8 + (sub >> 1)] = (f2b(po) << 16) | f2b(pv);
  }
}

// 16 lanes per node, bf16 t rows (32B). sub=lane&15: e=sub>>1 (8 edge slots),
// c=sub&1. Fast path deg<=32: 4 csr loads + 4 independent gathers. Row n of t
// is zeros. log_softmax via 8-local + xor-1 lane reduce. (R16-proven form.)
__global__ __launch_bounds__(256) void agg2_kernel(const uint4* __restrict__ t4,
                                                   const float* __restrict__ dinv,
                                                   const int* __restrict__ row_start,
                                                   const int* __restrict__ degs,
                                                   const int* __restrict__ csr,
                                                   const float* __restrict__ b2,
                                                   float* __restrict__ out, int n) {
  int idx = blockIdx.x * 256 + threadIdx.x;
  int v = idx >> 4;
  if (v >= n) return;
  int sub = threadIdx.x & 15;
  int e = sub >> 1, c = sub & 1;
  float dv = dinv[v];
  int rs = row_start[v], e1 = rs + degs[v];
  f2 A0[4];
#pragma unroll
  for (int k = 0; k < 4; ++k) A0[k] = {0.f, 0.f};
  {  // self loop
    int s = (e == 0) ? v : n;
    addu4(A0, t4[(size_t)s * 2 + c]);
  }
  int cv[4];
#pragma unroll
  for (int q = 0; q < 4; ++q) cv[q] = csr[rs + q * 8 + e];
  uint4 g[4];
#pragma unroll
  for (int q = 0; q < 4; ++q) {
    int k = rs + q * 8 + e;
    int s = (k < e1) ? cv[q] : n;
    g[q] = t4[(size_t)s * 2 + c];
  }
#pragma unroll
  for (int k = 0; k < 4; ++k) addu4(A0, g[k]);
  // tail: deg > 32 (rare; node-uniform)
  int i = rs + 32;
  while (i < e1) {
    int i0 = i + e;
    int sv = csr[i0];
    int s = (i0 < e1) ? sv : n;
    addu4(A0, t4[(size_t)s * 2 + c]);
    i += 8;
  }
#pragma unroll
  for (int m = 2; m <= 8; m <<= 1) {  // reduce across e-groups (sub bits 1..3)
#pragma unroll
    for (int k = 0; k < 4; ++k) {
      A0[k].x += __shfl_xor(A0[k].x, m, 64);
      A0[k].y += __shfl_xor(A0[k].y, m, 64);
    }
  }
  float4 bb0 = ((const float4*)b2)[c * 2];
  float4 bb1 = ((const float4*)b2)[c * 2 + 1];
  float z[8];
  z[0] = fmaf(dv, A0[0].x, bb0.x); z[1] = fmaf(dv, A0[0].y, bb0.y);
  z[2] = fmaf(dv, A0[1].x, bb0.z); z[3] = fmaf(dv, A0[1].y, bb0.w);
  z[4] = fmaf(dv, A0[2].x, bb1.x); z[5] = fmaf(dv, A0[2].y, bb1.y);
  z[6] = fmaf(dv, A0[3].x, bb1.z); z[7] = fmaf(dv, A0[3].y, bb1.w);
  float mx = z[0];
#pragma unroll
  for (int q = 1; q < 8; ++q) mx = fmaxf(mx, z[q]);
  mx = fmaxf(mx, __shfl_xor(mx, 1, 64));  // combine c halves
  float ss = 0.f;
#pragma unroll
  for (int q = 0; q < 8; ++q) ss += expf(z[q] - mx);
  ss += __shfl_xor(ss, 1, 64);
  float lg = mx + logf(ss);
  if (e == 0) {
    float4 r0 = make_float4(z[0] - lg, z[1] - lg, z[2] - lg, z[3] - lg);
    float4 r1 = make_float4(z[4] - lg, z[5] - lg, z[6] - lg, z[7] - lg);
    float4* o = (float4*)out + (size_t)v * 4 + c * 2;
    o[0] = r0;
    o[1] = r1;
  }
}

extern "C" void kernel_launch(void* const* d_in, const int* in_sizes, int n_in,
                              void* d_out, int out_size, void* d_ws, size_t ws_size,
                              hipStream_t stream) {
  const float* x = (const float*)d_in[0];
  const int* edge_index = (const int*)d_in[1];
  const float* W1 = (const float*)d_in[2];
  const float* b1 = (const float*)d_in[3];
  const float* W2 = (const float*)d_in[4];
  const float* b2 = (const float*)d_in[5];
  float* out = (float*)d_out;

  int N_ = in_sizes[0] / 128;
  int E_ = in_sizes[1] / 2;
  const int* src = edge_index;
  const int* dst = edge_index + E_;
  int NBc = (N_ + BMASK) >> BSHIFT;       // 196 buckets of 512 nodes
  int nSc = (E_ + CHUNK - 1) / CHUNK;     // 196 scatter blocks
  int nG1 = (N_ + 63) / 64;               // 1563 gemm1u blocks

  char* ws = (char*)d_ws;
  size_t off = 0;
  auto take = [&](size_t bytes) {
    void* p = ws + off;
    off += (bytes + 255) & ~(size_t)255;
    return p;
  };
  unsigned* h1s = (unsigned*)take(((size_t)N_ + 1) * 32 * 4);  // +1 zero row
  // region A: h1u (fp32, live until degcnt_scale) aliases {csr, t} (written
  // in agg1, after h1u is dead)
  size_t h1u_b = (size_t)N_ * 64 * 4;
  size_t csr_b = (((size_t)NBc * CAP + 64) * 4 + 255) & ~(size_t)255;
  size_t t_b = ((size_t)N_ + 1) * 8 * 4;
  size_t A_b = h1u_b > csr_b + t_b ? h1u_b : csr_b + t_b;
  char* A = (char*)take(A_b);
  float* h1u = (float*)A;
  int* csr = (int*)A;
  unsigned* t = (unsigned*)(A + csr_b);
  int* tmp = (int*)take((size_t)NBc * CAP * 4);
  float* dinv = (float*)take((size_t)N_ * 4);
  int* degs = (int*)take((size_t)N_ * 4);
  int* row_start = (int*)take((size_t)N_ * 4);
  int* gbcursor = (int*)take((size_t)NBc * 4);
  (void)ws_size;

  binit_kernel<<<(NBc + 255) / 256, 256, 0, stream>>>(gbcursor, NBc, h1s, N_);
  combo_kernel<<<nSc + nG1, 256, 0, stream>>>(src, dst, E_, NBc, nSc, gbcursor,
                                              tmp, x, W1, h1u, N_);
  degcnt_scale_kernel<<<NBc, 512, 0, stream>>>(tmp, gbcursor, (const float4*)h1u,
                                               degs, dinv, h1s, N_);
  agg1_fused_kernel<<<NBc, 1024, 0, stream>>>(tmp, gbcursor, (const uint4*)h1s,
                                              dinv, b1, W2, degs, row_start, csr,
                                              t, N_);
  agg2_kernel<<<(N_ * 16 + 255) / 256, 256, 0, stream>>>((const uint4*)t, dinv,
                                                         row_start, degs, csr,
                                                         b2, out, N_);
}

// Round 9
// 193.031 us; speedup vs baseline: 1.0860x; 1.0614x over previous
//
#include <hip/hip_runtime.h>
#include <math.h>

// ---------------------------------------------------------------------------
// 2-layer GCN. R21: best-of merge + direct-A gemm1.
// R20 post-mortem: combo overlap lost its own arithmetic (+38MB fp32 h1u
// round-trip, halved scatter parallelism) -> revert to R16's serial pipeline,
// which remains the best total (200.4). agg1 is at its random-gather memory
// wall (46.3-47.6 across SIX variants, FETCH ~80MB = 8 XCD-L2s re-missing the
// random 12.8MB h1s). This round only strictly-fewer-ops changes:
//  - gemm1: A-fragments loaded DIRECTLY from x (2 float4/ks per lane; same
//    bytes, same f2b count) -- drops the 17KB x-staging, one barrier, and
//    half the staging loop. Only W1^T is staged.
//  - agg1: R20's best variant (degs loaded from degcnt, deg-adaptive tiers
//    16/24/32, raw addu) at BSHIFT 9.
//  - agg2: R16 fixed-32 form with raw addu.
// ---------------------------------------------------------------------------

#define CHUNK 4096        // edges per scatterA block (391 blocks)
#define BSHIFT 9          // 512 nodes per bucket
#define BMASK 511
#define CAP 9216          // tmp/csr slots per bucket (mean 8192, +11 sigma)
#define CAPP (CAP + 40)   // LDS csr with fast-path overread pad

typedef __bf16 bf16x8 __attribute__((ext_vector_type(8)));
typedef float f32x4 __attribute__((ext_vector_type(4)));

__device__ __forceinline__ unsigned f2b(float f) {  // fp32 -> bf16 bits (RNE)
  unsigned u = __float_as_uint(f);
  return (u + 0x7FFF + ((u >> 16) & 1)) >> 16;
}

struct f2 { float x, y; };
__device__ __forceinline__ void addu(f2& a, unsigned u) {
  a.x += __uint_as_float(u << 16);
  a.y += __uint_as_float(u);  // low 16 bits are mantissa noise (<=0.4% rel)
}
__device__ __forceinline__ void addu4(f2* a, uint4 g) {
  addu(a[0], g.x); addu(a[1], g.y); addu(a[2], g.z); addu(a[3], g.w);
}

// init bucket cursors + zero rows n of h1s and t (masked-gather targets)
__global__ void binit_kernel(int* __restrict__ gbcursor, int nbc,
                             unsigned* __restrict__ h1s, unsigned* __restrict__ t,
                             int n) {
  int b = blockIdx.x * 256 + threadIdx.x;
  if (b < nbc) gbcursor[b] = b * CAP;
  if (blockIdx.x == 0) {
    if (threadIdx.x < 32) h1s[(size_t)n * 32 + threadIdx.x] = 0u;
    else if (threadIdx.x < 40) t[(size_t)n * 8 + (threadIdx.x - 32)] = 0u;
  }
}

// Block multisplit: pass1 LDS bucket hist; one global atomic per (block,bucket)
// reserves a segment; pass2 places edges via LDS cursors. pack=(src<<9)|(dst&511).
__global__ __launch_bounds__(256) void scatterA_kernel(const int* __restrict__ src,
                                                       const int* __restrict__ dst,
                                                       int E, int nbc,
                                                       int* __restrict__ gbcursor,
                                                       int* __restrict__ tmp) {
  __shared__ int hist[256];
  __shared__ int segcur[256];
  int tid = threadIdx.x;
  int estart = blockIdx.x * CHUNK;
  int eend = min(E, estart + CHUNK);
  hist[tid] = 0;
  __syncthreads();
  for (int i = estart + tid; i < eend; i += 256)
    atomicAdd(&hist[dst[i] >> BSHIFT], 1);
  __syncthreads();
  if (tid < nbc) {
    int c = hist[tid];
    segcur[tid] = c ? atomicAdd(&gbcursor[tid], c) : 0;
  }
  __syncthreads();
  for (int i = estart + tid; i < eend; i += 256) {
    int d = dst[i];
    int b = d >> BSHIFT;
    int pos = atomicAdd(&segcur[b], 1);
    if (pos < (b + 1) * CAP)  // statistically impossible overflow guard
      tmp[pos] = (src[i] << BSHIFT) | (d & BMASK);
  }
}

// Per-bucket in-degree histogram -> degs (reused by agg1) + dinv (for gemm1).
__global__ __launch_bounds__(512) void degcnt_kernel(const int* __restrict__ tmp,
                                                     const int* __restrict__ gbcursor,
                                                     int* __restrict__ degs,
                                                     float* __restrict__ dinv, int n) {
  __shared__ int nh[512];
  int b = blockIdx.x, tid = threadIdx.x;
  nh[tid] = 0;
  __syncthreads();
  int base = b * CAP;
  int count = min(gbcursor[b] - base, CAP);
  for (int i = tid; i < count; i += 512) atomicAdd(&nh[tmp[base + i] & BMASK], 1);
  __syncthreads();
  int v = (b << BSHIFT) + tid;
  if (v < n) {
    degs[v] = nh[tid];
    dinv[v] = rsqrtf((float)(nh[tid] + 1));
  }
}

// h1s[row] = bf16x2-packed dinv[row] * (x[row] @ W1), via MFMA.
// A-frags loaded directly from x (lane (m16,quad): x[row][ks*32+quad*8..+8],
// 2 float4 loads per ks); only W1^T staged in LDS (R9-proven b-frag layout).
__global__ __launch_bounds__(256, 4) void gemm1_kernel(const float* __restrict__ x,
                                                       const float* __restrict__ W1,
                                                       const float* __restrict__ dinv,
                                                       unsigned* __restrict__ h1s, int n) {
  __shared__ unsigned wt[64 * 68];   // wt16[n][k] bf16, stride 136 u16
  int tid = threadIdx.x;
  int vb = blockIdx.x * 64;

  unsigned short* wt16 = (unsigned short*)wt;
  const float4* wg = (const float4*)W1;
#pragma unroll
  for (int it = 0; it < 8; ++it) {
    int idx = it * 256 + tid;          // [0,2048): k = idx>>4, n0 = (idx&15)*4
    int k = idx >> 4, n0 = (idx & 15) * 4;
    float4 wv = wg[idx];
    wt16[(n0 + 0) * 136 + k] = (unsigned short)f2b(wv.x);
    wt16[(n0 + 1) * 136 + k] = (unsigned short)f2b(wv.y);
    wt16[(n0 + 2) * 136 + k] = (unsigned short)f2b(wv.z);
    wt16[(n0 + 3) * 136 + k] = (unsigned short)f2b(wv.w);
  }
  __syncthreads();

  int lane = tid & 63, wid = tid >> 6;
  int m16 = lane & 15, quad = lane >> 4;
  int row_a = vb + wid * 16 + m16;
  int ra = (row_a < n) ? row_a : n - 1;  // clamp: garbage only affects C row
                                         // m16 (guarded at store)
  const float4* xg = (const float4*)x + (size_t)ra * 32 + quad * 2;
  unsigned a32[4][4];                    // [ks][4 u32 = 8 bf16]
#pragma unroll
  for (int ks = 0; ks < 4; ++ks) {
    float4 v0 = xg[ks * 8];
    float4 v1 = xg[ks * 8 + 1];
    a32[ks][0] = (f2b(v0.y) << 16) | f2b(v0.x);
    a32[ks][1] = (f2b(v0.w) << 16) | f2b(v0.z);
    a32[ks][2] = (f2b(v1.y) << 16) | f2b(v1.x);
    a32[ks][3] = (f2b(v1.w) << 16) | f2b(v1.z);
  }
  const unsigned* wp = wt + m16 * 68 + quad * 4;
  f32x4 acc[4] = {};
#pragma unroll
  for (int ks = 0; ks < 4; ++ks) {
    bf16x8 a = *(const bf16x8*)a32[ks];
#pragma unroll
    for (int nt = 0; nt < 4; ++nt) {
      bf16x8 b = *(const bf16x8*)(wp + nt * 16 * 68 + ks * 16);
      acc[nt] = __builtin_amdgcn_mfma_f32_16x16x32_bf16(a, b, acc[nt], 0, 0, 0);
    }
  }
  // epilogue: C[row = quad*4+reg][col = nt*16+m16]; fold dinv, pack bf16
  int rbase = vb + wid * 16 + quad * 4;
  float dvv[4];
#pragma unroll
  for (int reg = 0; reg < 4; ++reg) {
    int row = rbase + reg;
    dvv[reg] = (row < n) ? dinv[row] : 0.f;
  }
  unsigned short* h16 = (unsigned short*)h1s;
#pragma unroll
  for (int nt = 0; nt < 4; ++nt) {
    int col = nt * 16 + m16;
#pragma unroll
    for (int reg = 0; reg < 4; ++reg) {
      int row = rbase + reg;
      if (row < n)
        h16[(size_t)row * 64 + col] = (unsigned short)f2b(dvv[reg] * acc[nt][reg]);
    }
  }
}

// NQ-tier gather batch for agg1: covers slots [0, 8*NQ) of the node's edge
// list. lcsr reads up to rs+8*NQ-1 (pad-safe); masked slots pull zero row n.
template <int NQ>
__device__ __forceinline__ void gatherTier1(const uint4* __restrict__ h1s4,
                                            const int* lcsr, int rs, int e1,
                                            int e, int c, int n, f2* a0) {
  int cv0[NQ], cv1[NQ];
#pragma unroll
  for (int q = 0; q < NQ; ++q) {
    cv0[q] = lcsr[rs + q * 8 + e];
    cv1[q] = lcsr[rs + q * 8 + 4 + e];
  }
  uint4 g[2 * NQ];
#pragma unroll
  for (int q = 0; q < NQ; ++q) {
    int k0 = rs + q * 8 + e, k1 = k0 + 4;
    int s0 = (k0 < e1) ? cv0[q] : n;
    int s1 = (k1 < e1) ? cv1[q] : n;
    g[2 * q] = h1s4[(size_t)s0 * 8 + c];
    g[2 * q + 1] = h1s4[(size_t)s1 * 8 + c];
  }
#pragma unroll
  for (int k = 0; k < 2 * NQ; ++k) addu4(a0, g[k]);
}

// One 1024-thr block per 512-node bucket: load degs -> scan -> LDS-cursor
// scatter -> coalesced csr dump -> walk (half-wave per node, deg-adaptive
// tiers 16/24/32, fused b1 + lrelu + MLP(64->16)) -> t bf16. (R20-proven.)
__global__ __launch_bounds__(1024) void agg1_fused_kernel(
    const int* __restrict__ tmp, const int* __restrict__ gbcursor,
    const uint4* __restrict__ h1s4, const float* __restrict__ dinv,
    const float* __restrict__ b1, const float* __restrict__ W2,
    const int* __restrict__ degs, int* __restrict__ row_start,
    int* __restrict__ csr, unsigned* __restrict__ t, int n) {
  __shared__ int lcsr[CAPP];       // 37KB
  __shared__ int nh[512];
  __shared__ int rs_s[512];
  __shared__ int lcur[512];
  __shared__ float W2s[64 * 17];
  __shared__ float b1s[64];
  __shared__ float a_s[16][2][64];
  int b = blockIdx.x, tid = threadIdx.x;
  int base = b * CAP;
  int count = min(gbcursor[b] - base, CAP);

  if (tid < 512) {
    int v = (b << BSHIFT) + tid;
    int d = (v < n) ? degs[v] : 0;
    nh[tid] = d;
    rs_s[tid] = d;
  }
  W2s[(tid >> 4) * 17 + (tid & 15)] = W2[tid];   // 1024 == 64*16
  if (tid < 64) b1s[tid] = b1[tid];
  __syncthreads();
  // exclusive scan of nh over 512
  for (int off = 1; off < 512; off <<= 1) {
    int a = 0;
    if (tid < 512) { a = rs_s[tid]; if (tid >= off) a += rs_s[tid - off]; }
    __syncthreads();
    if (tid < 512) rs_s[tid] = a;
    __syncthreads();
  }
  if (tid < 512) {
    int e0 = rs_s[tid] - nh[tid];   // exclusive prefix (bucket-local)
    lcur[tid] = e0;
    rs_s[tid] = e0;
    int v = (b << BSHIFT) + tid;
    if (v < n) row_start[v] = base + e0;
  }
  __syncthreads();
  // scatter into LDS csr
  for (int i = tid; i < count; i += 1024) {
    int val = tmp[base + i];
    int pos = atomicAdd(&lcur[val & BMASK], 1);
    lcsr[pos] = val >> BSHIFT;
  }
  __syncthreads();
  // coalesced dump for agg2
  for (int i = tid; i < count; i += 1024) csr[base + i] = lcsr[i];

  // walk
  int wave = tid >> 6, lane = tid & 63;
  int half = lane >> 5, sub = lane & 31;
  int e = sub >> 3, c = sub & 7;
  int j = sub & 15, grp = (sub >> 4) & 1;

#pragma unroll 1
  for (int it = 0; it < 16; ++it) {
    int nl = wave * 32 + it * 2 + half;       // 0..511
    int v = (b << BSHIFT) + nl;
    bool valid = (v < n);                     // half-uniform
    int rs = rs_s[nl];
    int deg = nh[nl];                         // 0 for v >= n
    int e1 = rs + deg;
    float dv = valid ? dinv[valid ? v : 0] : 0.f;

    f2 a0[4];
#pragma unroll
    for (int k = 0; k < 4; ++k) a0[k] = {0.f, 0.f};
    {  // self loop: e==0 lanes pull row v, others pull zero row
      int s = (valid && sub < 8) ? v : n;
      addu4(a0, h1s4[(size_t)s * 8 + c]);
    }
    // deg-adaptive fast path (wave-uniform tier on max of the two halves)
    int dm = max(deg, __shfl_xor(deg, 32, 64));
    int start;
    if (dm <= 16) {
      gatherTier1<2>(h1s4, lcsr, rs, e1, e, c, n, a0);
      start = 16;
    } else if (dm <= 24) {
      gatherTier1<3>(h1s4, lcsr, rs, e1, e, c, n, a0);
      start = 24;
    } else {
      gatherTier1<4>(h1s4, lcsr, rs, e1, e, c, n, a0);
      start = 32;
    }
    // tail: deg > 32 (rare)
    int i = rs + start;
    while (__any(i < e1)) {
      int i0 = i + e, i1 = i + 4 + e;
      int s0v = lcsr[i0];
      int s1v = lcsr[i1];
      int s0 = (i0 < e1) ? s0v : n;
      int s1 = (i1 < e1) ? s1v : n;
      addu4(a0, h1s4[(size_t)s0 * 8 + c]);
      addu4(a0, h1s4[(size_t)s1 * 8 + c]);
      i += 8;
    }
    // reduce across e (lane bits 3,4 within half)
#pragma unroll
    for (int m = 8; m <= 16; m <<= 1) {
#pragma unroll
      for (int k = 0; k < 4; ++k) {
        a0[k].x += __shfl_xor(a0[k].x, m, 64);
        a0[k].y += __shfl_xor(a0[k].y, m, 64);
      }
    }
    if (sub < 8) {  // e==0; c==sub; features 8c..8c+7
#pragma unroll
      for (int k = 0; k < 4; ++k) {
        float z0 = fmaf(dv, a0[k].x, b1s[8 * sub + 2 * k]);
        float z1 = fmaf(dv, a0[k].y, b1s[8 * sub + 2 * k + 1]);
        a_s[wave][half][8 * sub + 2 * k] = fmaxf(z0, 0.2f * z0);
        a_s[wave][half][8 * sub + 2 * k + 1] = fmaxf(z1, 0.2f * z1);
      }
    }
    // MLP 64->16: each half-lane sums 32 features (grp*16 and 32+grp*16)
    float p = 0.f;
#pragma unroll
    for (int q = 0; q < 16; ++q) {
      int f = grp * 16 + q;
      p = fmaf(a_s[wave][half][f], W2s[f * 17 + j], p);
    }
#pragma unroll
    for (int q = 0; q < 16; ++q) {
      int f = 32 + grp * 16 + q;
      p = fmaf(a_s[wave][half][f], W2s[f * 17 + j], p);
    }
    p += __shfl_xor(p, 16, 64);  // combine grp halves (lane bit 4)
    float pv = dv * p;
    float po = __shfl_xor(pv, 1, 64);
    if (valid && sub < 16 && !(sub & 1))
      t[(size_t)v * 8 + (sub >> 1)] = (f2b(po) << 16) | f2b(pv);
  }
}

// 16 lanes per node, bf16 t rows (32B). sub=lane&15: e=sub>>1 (8 edge slots),
// c=sub&1. Fast path deg<=32: 4 csr loads + 4 independent gathers. Row n of t
// is zeros. log_softmax via 8-local + xor-1 lane reduce. (R16-proven form.)
__global__ __launch_bounds__(256) void agg2_kernel(const uint4* __restrict__ t4,
                                                   const float* __restrict__ dinv,
                                                   const int* __restrict__ row_start,
                                                   const int* __restrict__ degs,
                                                   const int* __restrict__ csr,
                                                   const float* __restrict__ b2,
                                                   float* __restrict__ out, int n) {
  int idx = blockIdx.x * 256 + threadIdx.x;
  int v = idx >> 4;
  if (v >= n) return;
  int sub = threadIdx.x & 15;
  int e = sub >> 1, c = sub & 1;
  float dv = dinv[v];
  int rs = row_start[v], e1 = rs + degs[v];
  f2 A0[4];
#pragma unroll
  for (int k = 0; k < 4; ++k) A0[k] = {0.f, 0.f};
  {  // self loop
    int s = (e == 0) ? v : n;
    addu4(A0, t4[(size_t)s * 2 + c]);
  }
  int cv[4];
#pragma unroll
  for (int q = 0; q < 4; ++q) cv[q] = csr[rs + q * 8 + e];
  uint4 g[4];
#pragma unroll
  for (int q = 0; q < 4; ++q) {
    int k = rs + q * 8 + e;
    int s = (k < e1) ? cv[q] : n;
    g[q] = t4[(size_t)s * 2 + c];
  }
#pragma unroll
  for (int k = 0; k < 4; ++k) addu4(A0, g[k]);
  // tail: deg > 32 (rare; node-uniform)
  int i = rs + 32;
  while (i < e1) {
    int i0 = i + e;
    int sv = csr[i0];
    int s = (i0 < e1) ? sv : n;
    addu4(A0, t4[(size_t)s * 2 + c]);
    i += 8;
  }
#pragma unroll
  for (int m = 2; m <= 8; m <<= 1) {  // reduce across e-groups (sub bits 1..3)
#pragma unroll
    for (int k = 0; k < 4; ++k) {
      A0[k].x += __shfl_xor(A0[k].x, m, 64);
      A0[k].y += __shfl_xor(A0[k].y, m, 64);
    }
  }
  float4 bb0 = ((const float4*)b2)[c * 2];
  float4 bb1 = ((const float4*)b2)[c * 2 + 1];
  float z[8];
  z[0] = fmaf(dv, A0[0].x, bb0.x); z[1] = fmaf(dv, A0[0].y, bb0.y);
  z[2] = fmaf(dv, A0[1].x, bb0.z); z[3] = fmaf(dv, A0[1].y, bb0.w);
  z[4] = fmaf(dv, A0[2].x, bb1.x); z[5] = fmaf(dv, A0[2].y, bb1.y);
  z[6] = fmaf(dv, A0[3].x, bb1.z); z[7] = fmaf(dv, A0[3].y, bb1.w);
  float mx = z[0];
#pragma unroll
  for (int q = 1; q < 8; ++q) mx = fmaxf(mx, z[q]);
  mx = fmaxf(mx, __shfl_xor(mx, 1, 64));  // combine c halves
  float ss = 0.f;
#pragma unroll
  for (int q = 0; q < 8; ++q) ss += expf(z[q] - mx);
  ss += __shfl_xor(ss, 1, 64);
  float lg = mx + logf(ss);
  if (e == 0) {
    float4 r0 = make_float4(z[0] - lg, z[1] - lg, z[2] - lg, z[3] - lg);
    float4 r1 = make_float4(z[4] - lg, z[5] - lg, z[6] - lg, z[7] - lg);
    float4* o = (float4*)out + (size_t)v * 4 + c * 2;
    o[0] = r0;
    o[1] = r1;
  }
}

extern "C" void kernel_launch(void* const* d_in, const int* in_sizes, int n_in,
                              void* d_out, int out_size, void* d_ws, size_t ws_size,
                              hipStream_t stream) {
  const float* x = (const float*)d_in[0];
  const int* edge_index = (const int*)d_in[1];
  const float* W1 = (const float*)d_in[2];
  const float* b1 = (const float*)d_in[3];
  const float* W2 = (const float*)d_in[4];
  const float* b2 = (const float*)d_in[5];
  float* out = (float*)d_out;

  int N_ = in_sizes[0] / 128;
  int E_ = in_sizes[1] / 2;
  const int* src = edge_index;
  const int* dst = edge_index + E_;
  int NBc = (N_ + BMASK) >> BSHIFT;  // 196 buckets of 512 nodes (<= 256)

  char* ws = (char*)d_ws;
  size_t off = 0;
  auto take = [&](size_t bytes) {
    void* p = ws + off;
    off += (bytes + 255) & ~(size_t)255;
    return p;
  };
  unsigned* h1s = (unsigned*)take(((size_t)N_ + 1) * 32 * 4);  // +1 zero row
  unsigned* t = (unsigned*)take(((size_t)N_ + 1) * 8 * 4);     // +1 zero row
  int* tmp = (int*)take((size_t)NBc * CAP * 4);
  int* csr = (int*)take(((size_t)NBc * CAP + 64) * 4);         // padded layout
  float* dinv = (float*)take((size_t)N_ * 4);
  int* degs = (int*)take((size_t)N_ * 4);
  int* row_start = (int*)take((size_t)N_ * 4);
  int* gbcursor = (int*)take((size_t)NBc * 4);
  (void)ws_size;

  binit_kernel<<<(NBc + 255) / 256, 256, 0, stream>>>(gbcursor, NBc, h1s, t, N_);
  scatterA_kernel<<<(E_ + CHUNK - 1) / CHUNK, 256, 0, stream>>>(src, dst, E_, NBc,
                                                                gbcursor, tmp);
  degcnt_kernel<<<NBc, 512, 0, stream>>>(tmp, gbcursor, degs, dinv, N_);
  gemm1_kernel<<<(N_ + 63) / 64, 256, 0, stream>>>(x, W1, dinv, h1s, N_);
  agg1_fused_kernel<<<NBc, 1024, 0, stream>>>(tmp, gbcursor, (const uint4*)h1s,
                                              dinv, b1, W2, degs, row_start, csr,
                                              t, N_);
  agg2_kernel<<<(N_ * 16 + 255) / 256, 256, 0, stream>>>((const uint4*)t, dinv,
                                                         row_start, degs, csr,
                                                         b2, out, N_);
}